// Round 1
// baseline (351.375 us; speedup 1.0000x reference)
//
#include <hip/hip_runtime.h>
#include <stdint.h>

#define D_DIM 1024
#define T_DIM 4096
#define B_DIM 4
#define M_DIM 16384
#define NX 16777216UL
#define NW 1048576UL
#define LOG8F 2.0794415416798357f
#define CHUNK_L 128
#define NCHUNK 32

typedef __attribute__((ext_vector_type(4))) float f32x4;
typedef __attribute__((ext_vector_type(8))) short bf16x8;

__device__ __forceinline__ unsigned short f2bf(float f) {
    unsigned u = __float_as_uint(f);
    u += 0x7fffu + ((u >> 16) & 1u);
    return (unsigned short)(u >> 16);
}
__device__ __forceinline__ unsigned packbf2(float x, float y) {
    unsigned ux = __float_as_uint(x);
    ux = (ux + 0x7fffu + ((ux >> 16) & 1u)) >> 16;
    unsigned uy = __float_as_uint(y);
    uy = (uy + 0x7fffu + ((uy >> 16) & 1u)) & 0xffff0000u;
    return ux | uy;
}
__device__ __forceinline__ float unp_lo(unsigned p) { return __uint_as_float(p << 16); }
__device__ __forceinline__ float unp_hi(unsigned p) { return __uint_as_float(p & 0xffff0000u); }
__device__ __forceinline__ float sigm(float x) { return 1.0f / (1.0f + __expf(-x)); }

__device__ __forceinline__ void gl_lds16(const void* g, void* l) {
    __builtin_amdgcn_global_load_lds(
        (const __attribute__((address_space(1))) void*)g,
        (__attribute__((address_space(3))) void*)l, 16, 0, 0);
}

// ---------------------------------------------------------------------------
// Kernel 0: convert x, W_r, W_i, W_x  fp32 -> bf16 (4 elems/thread)
// ---------------------------------------------------------------------------
__global__ __launch_bounds__(256) void cvt_kernel(
    const float* __restrict__ x, const float* __restrict__ Wr,
    const float* __restrict__ Wi, const float* __restrict__ Wx,
    unsigned short* __restrict__ xb, unsigned short* __restrict__ wb)
{
    size_t tid = (size_t)blockIdx.x * 256 + threadIdx.x;
    size_t i = tid * 4;
    const float* src;
    unsigned short* dst;
    size_t off;
    if (i < NX) {
        src = x; dst = xb; off = i;
    } else {
        size_t j = i - NX;
        size_t w = j >> 20;           // / NW
        off = j & (NW - 1);
        src = (w == 0) ? Wr : (w == 1 ? Wi : Wx);
        dst = wb + w * NW;
    }
    float4 v = *(const float4*)(src + off);
    ushort4 o;
    o.x = f2bf(v.x); o.y = f2bf(v.y); o.z = f2bf(v.z); o.w = f2bf(v.w);
    *(ushort4*)(dst + off) = o;
}

// ---------------------------------------------------------------------------
// Kernel 1: fused GEMM (3 weights sequentially per 128x128 tile) + gating
//   writes a (fp32) to ws, u (fp32) to d_out (scan later overwrites in place)
// ---------------------------------------------------------------------------
__global__ __launch_bounds__(256, 2) void fused_gemm(
    const unsigned short* __restrict__ xb, const unsigned short* __restrict__ wb,
    const float* __restrict__ b_r, const float* __restrict__ b_i,
    float* __restrict__ a_out, float* __restrict__ u_out)
{
    __shared__ __align__(16) unsigned short As[128 * 32];
    __shared__ __align__(16) unsigned short Bs[128 * 32];

    const int tid  = threadIdx.x;
    const int lane = tid & 63;
    const int wave = tid >> 6;
    const int wm = wave & 1;
    const int wn = wave >> 1;
    const int m0 = (blockIdx.x >> 3) * 128;
    const int d0 = (blockIdx.x & 7) * 128;
    const int frow = lane & 15;
    const int kgrp = lane >> 4;

    const int r0 = tid >> 2;            // staging row for chunk tid
    const int c0 = (tid & 3) << 3;      // k-offset within tile (x8 bf16)
    const unsigned short* xrow = xb + (size_t)m0 * D_DIM;

    unsigned gip[4][4][2];              // packed bf16 persistent: gate, then gate*i

    for (int w = 0; w < 3; ++w) {
        const unsigned short* wrow = wb + (size_t)w * NW + (size_t)d0 * D_DIM;
        f32x4 acc[4][4];
        #pragma unroll
        for (int i = 0; i < 4; i++)
            #pragma unroll
            for (int j = 0; j < 4; j++) acc[i][j] = (f32x4){0.f, 0.f, 0.f, 0.f};

        for (int kk = 0; kk < 32; ++kk) {
            const int k0 = kk << 5;
            gl_lds16(xrow + (size_t)r0 * D_DIM + k0 + c0,        &As[tid * 8]);
            gl_lds16(xrow + (size_t)(r0 + 64) * D_DIM + k0 + c0, &As[(tid + 256) * 8]);
            gl_lds16(wrow + (size_t)r0 * D_DIM + k0 + c0,        &Bs[tid * 8]);
            gl_lds16(wrow + (size_t)(r0 + 64) * D_DIM + k0 + c0, &Bs[(tid + 256) * 8]);
            __syncthreads();
            bf16x8 af[4], bfr[4];
            #pragma unroll
            for (int i = 0; i < 4; i++)
                af[i] = *(const bf16x8*)&As[(wm * 64 + i * 16 + frow) * 32 + kgrp * 8];
            #pragma unroll
            for (int j = 0; j < 4; j++)
                bfr[j] = *(const bf16x8*)&Bs[(wn * 64 + j * 16 + frow) * 32 + kgrp * 8];
            #pragma unroll
            for (int i = 0; i < 4; i++)
                #pragma unroll
                for (int j = 0; j < 4; j++)
                    acc[i][j] = __builtin_amdgcn_mfma_f32_16x16x32_bf16(
                        af[i], bfr[j], acc[i][j], 0, 0, 0);
            __syncthreads();
        }

        // Epilogue. C/D layout: col(d) = lane&15, row(m) = (lane>>4)*4 + r.
        const int mb = m0 + wm * 64;
        const int db = d0 + wn * 64;
        if (w == 0) {
            #pragma unroll
            for (int j = 0; j < 4; j++) {
                const int d = db + j * 16 + frow;
                const float br = b_r[d];
                #pragma unroll
                for (int i = 0; i < 4; i++) {
                    float g[4];
                    #pragma unroll
                    for (int r = 0; r < 4; r++) {
                        const int m = mb + i * 16 + kgrp * 4 + r;
                        float rg = sigm(acc[i][j][r] + br);
                        // exp(-softplus(z)) == sigmoid(-z)
                        float a = sigm(-LOG8F * rg);
                        a_out[(size_t)m * D_DIM + d] = a;
                        g[r] = sqrtf(fmaxf(1.0f - a * a, 1e-6f));
                    }
                    gip[i][j][0] = packbf2(g[0], g[1]);
                    gip[i][j][1] = packbf2(g[2], g[3]);
                }
            }
        } else if (w == 1) {
            #pragma unroll
            for (int j = 0; j < 4; j++) {
                const int d = db + j * 16 + frow;
                const float bi = b_i[d];
                #pragma unroll
                for (int i = 0; i < 4; i++) {
                    float g0 = unp_lo(gip[i][j][0]) * sigm(acc[i][j][0] + bi);
                    float g1 = unp_hi(gip[i][j][0]) * sigm(acc[i][j][1] + bi);
                    float g2 = unp_lo(gip[i][j][1]) * sigm(acc[i][j][2] + bi);
                    float g3 = unp_hi(gip[i][j][1]) * sigm(acc[i][j][3] + bi);
                    gip[i][j][0] = packbf2(g0, g1);
                    gip[i][j][1] = packbf2(g2, g3);
                }
            }
        } else {
            #pragma unroll
            for (int j = 0; j < 4; j++) {
                const int d = db + j * 16 + frow;
                #pragma unroll
                for (int i = 0; i < 4; i++) {
                    #pragma unroll
                    for (int r = 0; r < 4; r++) {
                        const int m = mb + i * 16 + kgrp * 4 + r;
                        float gi = (r & 1) ? unp_hi(gip[i][j][r >> 1])
                                           : unp_lo(gip[i][j][r >> 1]);
                        u_out[(size_t)m * D_DIM + d] = gi * acc[i][j][r];
                    }
                }
            }
        }
    }
}

// ---------------------------------------------------------------------------
// Kernel 2: per-chunk local scan (h_init = 0): A = prod a, H = local scan end
// ---------------------------------------------------------------------------
__global__ __launch_bounds__(256) void scan_phase1(
    const float* __restrict__ a, const float* __restrict__ u,
    float* __restrict__ Ac, float* __restrict__ Hc)
{
    int tid = blockIdx.x * 256 + threadIdx.x;   // (b*NCHUNK + c)*D + d
    int d = tid & (D_DIM - 1);
    int bc = tid >> 10;
    int b = bc >> 5;
    int c = bc & (NCHUNK - 1);
    size_t base = ((size_t)b * T_DIM + (size_t)c * CHUNK_L) * D_DIM + d;
    float A = 1.0f, H = 0.0f;
    for (int t = 0; t < CHUNK_L; t++) {
        float at = a[base + (size_t)t * D_DIM];
        float ut = u[base + (size_t)t * D_DIM];
        H = at * H + ut;
        A *= at;
    }
    Ac[tid] = A;
    Hc[tid] = H;
}

// ---------------------------------------------------------------------------
// Kernel 3: inter-chunk scan (tiny): chunk-start h values + h_last
// ---------------------------------------------------------------------------
__global__ __launch_bounds__(256) void scan_phase2(
    const float* __restrict__ h0,
    const float* __restrict__ Ac, const float* __restrict__ Hc,
    float* __restrict__ hstart, float* __restrict__ hlast)
{
    int tid = blockIdx.x * 256 + threadIdx.x;   // b*D + d
    int d = tid & (D_DIM - 1);
    int b = tid >> 10;
    float h = h0[tid];
    for (int c = 0; c < NCHUNK; c++) {
        size_t idx = ((size_t)(b * NCHUNK + c)) * D_DIM + d;
        hstart[idx] = h;
        h = Ac[idx] * h + Hc[idx];
    }
    hlast[tid] = h;
}

// ---------------------------------------------------------------------------
// Kernel 4: apply — recompute local scan with true h_start, overwrite u -> h
// ---------------------------------------------------------------------------
__global__ __launch_bounds__(256) void scan_phase3(
    const float* __restrict__ a, const float* __restrict__ hstart,
    float* __restrict__ out)
{
    int tid = blockIdx.x * 256 + threadIdx.x;
    int d = tid & (D_DIM - 1);
    int bc = tid >> 10;
    int b = bc >> 5;
    int c = bc & (NCHUNK - 1);
    size_t base = ((size_t)b * T_DIM + (size_t)c * CHUNK_L) * D_DIM + d;
    float h = hstart[tid];
    for (int t = 0; t < CHUNK_L; t++) {
        size_t idx = base + (size_t)t * D_DIM;
        float at = a[idx];
        float ut = out[idx];
        h = at * h + ut;
        out[idx] = h;
    }
}

// ---------------------------------------------------------------------------
extern "C" void kernel_launch(void* const* d_in, const int* in_sizes, int n_in,
                              void* d_out, int out_size, void* d_ws, size_t ws_size,
                              hipStream_t stream)
{
    const float* x  = (const float*)d_in[0];
    const float* h0 = (const float*)d_in[1];
    const float* Wr = (const float*)d_in[2];
    const float* br = (const float*)d_in[3];
    const float* Wi = (const float*)d_in[4];
    const float* bi = (const float*)d_in[5];
    const float* Wx = (const float*)d_in[6];
    float* out = (float*)d_out;

    char* ws = (char*)d_ws;
    unsigned short* xb = (unsigned short*)ws;                          // 32 MB
    unsigned short* wb = (unsigned short*)(ws + 33554432);             // 6 MB
    float* a_buf = (float*)(ws + 33554432 + 6291456);                  // 64 MB
    char* tail = ws + 33554432 + 6291456 + 67108864;
    float* Ac = (float*)tail;                                          // 512 KB
    float* Hc = Ac + (size_t)B_DIM * NCHUNK * D_DIM;                   // 512 KB
    float* hstart = Hc + (size_t)B_DIM * NCHUNK * D_DIM;               // 512 KB

    // 0: fp32 -> bf16 (x and the three weights)
    cvt_kernel<<<19456, 256, 0, stream>>>(x, Wr, Wi, Wx, xb, wb);
    // 1: fused GEMM + gating. a -> ws, u -> d_out
    fused_gemm<<<1024, 256, 0, stream>>>(xb, wb, br, bi, a_buf, out);
    // 2-4: chunked scan
    scan_phase1<<<512, 256, 0, stream>>>(a_buf, out, Ac, Hc);
    scan_phase2<<<16, 256, 0, stream>>>(h0, Ac, Hc, hstart,
                                        out + (size_t)M_DIM * D_DIM);
    scan_phase3<<<512, 256, 0, stream>>>(a_buf, hstart, out);
}